// Round 5
// baseline (88.541 us; speedup 1.0000x reference)
//
#include <hip/hip_runtime.h>

#define C_    19
#define NB    15
#define CB    (C_ * NB)          // 285 cells
#define HW    (512 * 1024)
#define NPIX  (4 * HW)           // 2097152
#define REPS  8                  // LDS replicas for rare bin>=2 atomics
#define TPB   256
#define GBLK  1024               // 4 blocks/CU, 8 pixels/thread
#define KCOP  8                  // global histogram copies

// Merged-cell trick: per (class,bin), |conf_sum - acc_sum| only needs
// cell += conf - (c==label). Bins 0/1 in registers (d0/d1), bin>=2 via LDS
// atomics. No max-subtraction (|logit|<6, exp can't overflow; ~1ulp conf diff).
// exp computed in place over the float2 components -> live state ~91 regs.
__global__ __launch_bounds__(TPB, 4)
void ece_hist(const float* __restrict__ logits,
              const int*   __restrict__ labels,
              float*       __restrict__ ws) {
    __shared__ float hist[REPS * CB];    // 9120 B

    const int tid = threadIdx.x;
    for (int i = tid; i < REPS * CB; i += TPB) hist[i] = 0.f;
    __syncthreads();

    float* myh = hist + (tid & (REPS - 1)) * CB;

    float d0[C_], d1[C_];                // merged (conf - acc) accumulators, bins 0/1
#pragma unroll
    for (int c = 0; c < C_; ++c) { d0[c] = 0.f; d1[c] = 0.f; }

    for (int g = blockIdx.x * TPB + tid; g < NPIX / 2; g += GBLK * TPB) {
        const int n  = g << 1;                     // 2 consecutive pixels
        const int b  = n >> 19;                    // HW = 2^19; pairs never straddle b
        const int hw = n & (HW - 1);
        const float* base = logits + ((size_t)b * C_) * HW + hw;

        float2 v[C_];
#pragma unroll
        for (int c = 0; c < C_; ++c)
            v[c] = *reinterpret_cast<const float2*>(base + (size_t)c * HW);
        const int2 lab = *reinterpret_cast<const int2*>(labels + n);

        // ---- pixel 0: exp in place over .x ----
        float s0 = 0.f;
#pragma unroll
        for (int c = 0; c < C_; ++c) { v[c].x = __expf(v[c].x); s0 += v[c].x; }
        {
            const float inv = 1.f / s0;
            const int l = lab.x;
#pragma unroll
            for (int c = 0; c < C_; ++c) {
                const float conf = v[c].x * inv;
                int bin = (int)ceilf(conf * (float)NB) - 1;   // reference binning
                bin = bin < 0 ? 0 : (bin > NB - 1 ? NB - 1 : bin);
                const float val = conf - ((c == l) ? 1.f : 0.f);  // conf>0 always here
                d0[c] += (bin == 0) ? val : 0.f;
                d1[c] += (bin == 1) ? val : 0.f;
                if (bin >= 2) atomicAdd(&myh[c * NB + bin], val);
            }
        }
        // ---- pixel 1: exp in place over .y ----
        float s1 = 0.f;
#pragma unroll
        for (int c = 0; c < C_; ++c) { v[c].y = __expf(v[c].y); s1 += v[c].y; }
        {
            const float inv = 1.f / s1;
            const int l = lab.y;
#pragma unroll
            for (int c = 0; c < C_; ++c) {
                const float conf = v[c].y * inv;
                int bin = (int)ceilf(conf * (float)NB) - 1;
                bin = bin < 0 ? 0 : (bin > NB - 1 ? NB - 1 : bin);
                const float val = conf - ((c == l) ? 1.f : 0.f);
                d0[c] += (bin == 0) ? val : 0.f;
                d1[c] += (bin == 1) ? val : 0.f;
                if (bin >= 2) atomicAdd(&myh[c * NB + bin], val);
            }
        }
    }

    // Flush register accumulators: 3-step xor-shuffle (8-lane groups) then
    // GLOBAL atomics from leaders (keeps the DS pipe free for main-loop atomics).
    float* wsb = ws + (size_t)(blockIdx.x & (KCOP - 1)) * CB;
#pragma unroll
    for (int c = 0; c < C_; ++c) {
        float v0 = d0[c], v1 = d1[c];
        v0 += __shfl_xor(v0, 1); v1 += __shfl_xor(v1, 1);
        v0 += __shfl_xor(v0, 2); v1 += __shfl_xor(v1, 2);
        v0 += __shfl_xor(v0, 4); v1 += __shfl_xor(v1, 4);
        if ((tid & 7) == 0) {
            atomicAdd(&wsb[c * NB + 0], v0);
            atomicAdd(&wsb[c * NB + 1], v1);
        }
    }
    __syncthreads();

    // Fold LDS replicas (bin>=2 cells) into global. Bins 0/1 cells are 0 -> skipped.
    for (int i = tid; i < CB; i += TPB) {
        float s = 0.f;
#pragma unroll
        for (int r = 0; r < REPS; ++r) s += hist[r * CB + i];
        if (s != 0.f) atomicAdd(&wsb[i], s);
    }
}

// Fold KCOP copies: sce = sum_cells |cell| / (N * C)
__global__ void ece_final(const float* __restrict__ ws, float* __restrict__ out) {
    const int t = threadIdx.x;  // 320 threads = 5 waves
    float val = 0.f;
    if (t < CB) {
        float s = 0.f;
#pragma unroll
        for (int k = 0; k < KCOP; ++k) s += ws[k * CB + t];
        val = fabsf(s);
    }
#pragma unroll
    for (int off = 32; off; off >>= 1) val += __shfl_down(val, off);
    __shared__ float sm[5];
    if ((t & 63) == 0) sm[t >> 6] = val;
    __syncthreads();
    if (t == 0) {
        float tot = sm[0] + sm[1] + sm[2] + sm[3] + sm[4];
        out[0] = tot / ((float)NPIX * (float)C_);
    }
}

extern "C" void kernel_launch(void* const* d_in, const int* in_sizes, int n_in,
                              void* d_out, int out_size, void* d_ws, size_t ws_size,
                              hipStream_t stream) {
    const float* logits = (const float*)d_in[0];
    const int*   labels = (const int*)d_in[1];
    float* out = (float*)d_out;
    float* ws  = (float*)d_ws;

    hipMemsetAsync(ws, 0, (size_t)KCOP * CB * sizeof(float), stream);
    ece_hist<<<GBLK, TPB, 0, stream>>>(logits, labels, ws);
    ece_final<<<1, 320, 0, stream>>>(ws, out);
}